// Round 6
// baseline (173.279 us; speedup 1.0000x reference)
//
#include <hip/hip_runtime.h>
#include <stdint.h>
#include <math.h>

// Problem shape (fixed by reference): xs [B,T,N,D] fp32, A [1,N,N] int32
#define BB 4
#define TT 32
#define NN 128
#define DD 32
#define NPB 8                        // nodes per block (8 nodes x 32 d = 256 threads)
#define NBLK (BB * TT * (NN / NPB))  // 2048 blocks
#define SROW 33                      // padded LDS row stride (floats) for sval: bank (j+d)%32

// Monotone non-decreasing 8-bin partition (trunc-toward-zero is still monotone;
// bin0 = x < -0.6 incl. tail, bin7 = x >= 0.6 incl. tail, interior width 0.2).
// Any monotone partition gives exact rank selection; overflow -> exact fallback.
__device__ __forceinline__ int bin8(float x) {
    int i = (int)fmaf(x, 5.0f, 4.0f);
    i = i < 0 ? 0 : i;
    return i > 7 ? 7 : i;
}

// Build per-node neighbor bitmasks (A row + self loop) and u8 id list (fallback only).
__global__ __launch_bounds__(64) void build_adj_kernel(const int* __restrict__ A,
                                                       uint8_t* __restrict__ nbr,
                                                       unsigned long long* __restrict__ nmask) {
    const int n = blockIdx.x;
    const int lane = threadIdx.x;  // 0..63
    const int* arow = A + n * NN;
    uint8_t* row = nbr + n * NN;
    const int j0 = lane, j1 = lane + 64;
    const bool b0 = (arow[j0] != 0) || (j0 == n);
    const bool b1 = (arow[j1] != 0) || (j1 == n);
    const unsigned long long m0 = __ballot(b0);
    const unsigned long long m1 = __ballot(b1);
    const unsigned long long lmask = (1ULL << lane) - 1ULL;
    const int c0 = __popcll(m0);
    if (b0) row[__popcll(m0 & lmask)] = (uint8_t)j0;
    if (b1) row[c0 + __popcll(m1 & lmask)] = (uint8_t)j1;
    if (lane == 0) { nmask[2 * n] = m0; nmask[2 * n + 1] = m1; }
}

// Plain __launch_bounds__(256): R3 proved a waves/EU hint forces scratch spills
// (~430 MB spill traffic). LDS = 16.5K sval + 4.25K smask = 21.2 KB -> 7 blocks/CU.
__global__ __launch_bounds__(256) void median_kernel(const float* __restrict__ xs,
                                                     const uint8_t* __restrict__ nbr,
                                                     const unsigned long long* __restrict__ nmask,
                                                     float* __restrict__ out) {
    __shared__ float sval[NN * SROW];               // 16.9 KB padded frame
    __shared__ unsigned long long smask[DD][17];    // 4.25 KB bin masks; [d][bin*2+half], slot16=pad

    const int tid = threadIdx.x;
    const int g = blockIdx.x;
    const int ng = g % (NN / NPB);
    const int t  = (g / (NN / NPB)) % TT;
    const int b  = g / ((NN / NPB) * TT);
    const int n0 = ng * NPB;

    const int d = tid & (DD - 1);
    const int nl = tid >> 5;
    const int n = n0 + nl;
    const int pv = (t > 0) ? 1 : 0;       // wave-uniform
    const int nv = (t < TT - 1) ? 1 : 0;  // wave-uniform

    // temporal candidates (coalesced), own-node neighbor bitmask
    float xprev = 0.0f, xnext = 0.0f;
    if (pv) xprev = xs[(((size_t)(b * TT + t - 1) * NN) + n) * DD + d];
    if (nv) xnext = xs[(((size_t)(b * TT + t + 1) * NN) + n) * DD + d];
    const unsigned long long nm0 = nmask[2 * n];
    const unsigned long long nm1 = nmask[2 * n + 1];

    // stage frame into padded LDS (coalesced float4 global reads, 4x b32 writes)
    const float4* src4 = (const float4*)(xs + ((size_t)(b * TT + t) * NN) * DD);
    #pragma unroll
    for (int s = 0; s < 4; ++s) {
        int i4 = tid + (s << 8);
        float4 v = src4[i4];
        int e = i4 << 2;
        float* dst = &sval[(e >> 5) * SROW + (e & 31)];
        dst[0] = v.x; dst[1] = v.y; dst[2] = v.z; dst[3] = v.w;
    }
    __syncthreads();

    // build bin masks: 64 tasks (32 d x 2 j-halves), 4 waves x 16 steps, ballot per bin
    {
        const int w = tid >> 6;
        const int lane = tid & 63;
        for (int s = 0; s < 16; ++s) {
            int task = s * 4 + w;
            int td = task >> 1;
            int half = task & 1;
            int j = half * 64 + lane;
            float x = sval[j * SROW + td];   // bank (j+td)%32: 2-way, free
            int bx = bin8(x);
            #pragma unroll
            for (int bb = 0; bb < 8; ++bb) {
                unsigned long long m = __ballot(bx == bb);
                if (lane == 0) smask[td][bb * 2 + half] = m;
            }
        }
    }
    __syncthreads();

    const int deg = __popcll(nm0) + __popcll(nm1);
    const int k = deg + pv + nv;
    const uint32_t r = (uint32_t)((k - 1) >> 1);  // lower-median rank (0-based)
    const float INFV = __uint_as_float(0x7F800000u);
    const int tb0 = bin8(xprev), tb1 = bin8(xnext);  // guarded by pv/nv below

    // ---- census: 8 masked popcounts (no value reads) ----
    uint32_t c[8];
    #pragma unroll
    for (int bb = 0; bb < 8; ++bb) {
        unsigned long long b0 = smask[d][bb * 2], b1 = smask[d][bb * 2 + 1];
        c[bb] = (uint32_t)(__popcll(nm0 & b0) + __popcll(nm1 & b1))
              + (uint32_t)(pv && tb0 == bb) + (uint32_t)(nv && tb1 == bb);
    }
    // prefix + select bin containing rank r
    uint32_t cum = 0, lowcnt = 0; int selbin = -1;
    #pragma unroll
    for (int bb = 0; bb < 8; ++bb) {
        uint32_t ncum = cum + c[bb];
        if (selbin < 0 && r < ncum) { selbin = bb; lowcnt = cum; }
        cum = ncum;
    }
    unsigned long long band0 = nm0 & smask[d][selbin * 2];
    unsigned long long band1 = nm1 & smask[d][selbin * 2 + 1];
    const int mcm = __popcll(band0) + __popcll(band1);
    const bool fb = (mcm > 16);           // only fallback: band too big for registers
    if (fb) { band0 = 0; band1 = 0; }
    const uint32_t rp = r - lowcnt;       // rank within band

    // ---- extraction: walk set bits straight into registers (static unroll) ----
    float ki[18];
    {
        unsigned long long m0 = band0, m1 = band1;
        #pragma unroll
        for (int u = 0; u < 16; ++u) {
            bool lo = (m0 != 0ull);
            int jj0 = __ffsll(m0) - 1;
            int jj1 = (m1 != 0ull) ? (__ffsll(m1) + 63) : 127;
            int j = lo ? jj0 : jj1;
            float x = sval[j * SROW + d];   // lanes d consecutive: conflict-free
            ki[u] = (u < mcm) ? x : INFV;
            unsigned long long t1 = m1 & (m1 - 1ull);
            m0 = m0 & (m0 - 1ull);
            m1 = lo ? m1 : t1;
        }
    }
    const bool tv0 = pv && (tb0 == selbin) && !fb;
    const bool tv1 = nv && (tb1 == selbin) && !fb;
    ki[16] = tv0 ? xprev : INFV;
    ki[17] = tv1 ? xnext : INFV;

    // ---- register-resident counting selection (18x18 fully unrolled) ----
    uint32_t cn[18];
    #pragma unroll
    for (int u = 0; u < 18; ++u) cn[u] = 0;
    #pragma unroll
    for (int j = 0; j < 18; ++j) {
        float kj = ki[j];
        #pragma unroll
        for (int u = 0; u < 18; ++u) cn[u] += (kj < ki[u]);
    }
    float result = 0.0f;
    bool found = fb;
    #pragma unroll
    for (int u = 0; u < 18; ++u) {
        bool valid = (u < 16) ? (u < mcm) : (u == 16 ? tv0 : tv1);
        if (!found && valid && cn[u] == rp) { result = ki[u]; found = true; }
    }

    // ---- duplicate-median pass (exact multiset lower-median; ~never runs) ----
    if (__ballot(!found)) {
        #pragma unroll
        for (int u = 0; u < 18; ++u) {
            bool valid = (u < 16) ? (u < mcm) : (u == 16 ? tv0 : tv1);
            uint32_t le = 0;
            #pragma unroll
            for (int j = 0; j < 18; ++j) le += (ki[j] <= ki[u]);
            if (!found && valid && cn[u] <= rp && rp < le) { result = ki[u]; found = true; }
        }
    }

    // ---- full fallback (band > 16; ~1e-5 of lanes): exact scan over all k ----
    if (__ballot(fb)) {
        const uint8_t* nb = nbr + (size_t)n * NN;   // global; only fb lanes touch it
        bool done = !fb;
        for (int i0 = 0; __ballot(!done) && i0 < 132; i0 += 4) {
            if (!done) {
                float k4[4]; uint32_t lt4[4], le4[4];
                #pragma unroll
                for (int u = 0; u < 4; ++u) {
                    int i = i0 + u;
                    float v;
                    if (i < deg) v = sval[nb[i] * SROW + d];
                    else if (i == deg && pv) v = xprev;
                    else if (i == deg + pv && i < k) v = xnext;
                    else v = INFV;
                    k4[u] = (i < k) ? v : INFV;
                    lt4[u] = 0; le4[u] = 0;
                }
                for (int j = 0; j < deg; ++j) {
                    float xv = sval[nb[j] * SROW + d];
                    #pragma unroll
                    for (int u = 0; u < 4; ++u) { lt4[u] += (xv < k4[u]); le4[u] += (xv <= k4[u]); }
                }
                if (pv) {
                    #pragma unroll
                    for (int u = 0; u < 4; ++u) { lt4[u] += (xprev < k4[u]); le4[u] += (xprev <= k4[u]); }
                }
                if (nv) {
                    #pragma unroll
                    for (int u = 0; u < 4; ++u) { lt4[u] += (xnext < k4[u]); le4[u] += (xnext <= k4[u]); }
                }
                #pragma unroll
                for (int u = 0; u < 4; ++u) {
                    if (!done && (i0 + u) < k && lt4[u] <= r && r < le4[u]) {
                        result = k4[u]; done = true;
                    }
                }
            }
        }
    }

    out[(((size_t)(b * TT + t) * NN) + n) * DD + d] = result;
}

extern "C" void kernel_launch(void* const* d_in, const int* in_sizes, int n_in,
                              void* d_out, int out_size, void* d_ws, size_t ws_size,
                              hipStream_t stream) {
    const float* xs = (const float*)d_in[0];
    const int* A = (const int*)d_in[1];
    float* out = (float*)d_out;

    // workspace: nbr u8[128*128] (16 KB) | nmask u64[128][2] (2 KB)
    uint8_t* nbr = (uint8_t*)d_ws;
    unsigned long long* nmask = (unsigned long long*)((char*)d_ws + NN * NN);

    build_adj_kernel<<<NN, 64, 0, stream>>>(A, nbr, nmask);
    median_kernel<<<NBLK, 256, 0, stream>>>(xs, nbr, nmask, out);
}

// Round 7
// 171.397 us; speedup vs baseline: 1.0110x; 1.0110x over previous
//
#include <hip/hip_runtime.h>
#include <stdint.h>
#include <math.h>

// Problem shape (fixed by reference): xs [B,T,N,D] fp32, A [1,N,N] int32
#define BB 4
#define TT 32
#define NN 128
#define DD 32
#define NPB 8                        // nodes per block (8 nodes x 32 d = 256 threads)
#define NBLK (BB * TT * (NN / NPB))  // 2048 blocks
#define CAP 16                       // band list capacity; overflow -> exact fallback

// Monotone non-decreasing 8-bin partition (bin0: x<-0.6 incl tail, bin7: x>=0.6
// incl tail, interior width 0.2). Any monotone partition gives exact rank
// selection; selected-bin overflow -> exact fallback. Proven in R5/R6.
__device__ __forceinline__ int bin8(float x) {
    int i = (int)fmaf(x, 5.0f, 4.0f);
    i = i < 0 ? 0 : i;
    return i > 7 ? 7 : i;
}

// Per-node neighbor bitmasks (A row + self loop) and u8 id list (fallback only).
__global__ __launch_bounds__(64) void build_adj_kernel(const int* __restrict__ A,
                                                       uint8_t* __restrict__ nbr,
                                                       unsigned long long* __restrict__ nmask) {
    const int n = blockIdx.x;
    const int lane = threadIdx.x;  // 0..63
    const int* arow = A + n * NN;
    uint8_t* row = nbr + n * NN;
    const int j0 = lane, j1 = lane + 64;
    const bool b0 = (arow[j0] != 0) || (j0 == n);
    const bool b1 = (arow[j1] != 0) || (j1 == n);
    const unsigned long long m0 = __ballot(b0);
    const unsigned long long m1 = __ballot(b1);
    const unsigned long long lmask = (1ULL << lane) - 1ULL;
    const int c0 = __popcll(m0);
    if (b0) row[__popcll(m0 & lmask)] = (uint8_t)j0;
    if (b1) row[c0 + __popcll(m1 & lmask)] = (uint8_t)j1;
    if (lane == 0) { nmask[2 * n] = m0; nmask[2 * n + 1] = m1; }
}

// Per-frame bin-membership masks: gmask[bt][bin][q][d] (u32, q = j/32 quarter).
// One block per (b,t); ballots over j. Frame is tiny (16 KB); kernel is ~1% of total.
__global__ __launch_bounds__(256) void build_masks_kernel(const float* __restrict__ xs,
                                                          uint32_t* __restrict__ gmask) {
    __shared__ float spad[NN * 33];  // padded: j-across-lanes reads bank (j+d)%32, conflict-free
    const int bt = blockIdx.x;
    const int tid = threadIdx.x;
    const float4* src4 = (const float4*)(xs + (size_t)bt * NN * DD);
    #pragma unroll
    for (int s = 0; s < 4; ++s) {
        int i4 = tid + (s << 8);
        float4 v = src4[i4];
        int e = i4 << 2;
        float* dst = &spad[(e >> 5) * 33 + (e & 31)];
        dst[0] = v.x; dst[1] = v.y; dst[2] = v.z; dst[3] = v.w;
    }
    __syncthreads();
    const int w = tid >> 6, lane = tid & 63;
    for (int s = 0; s < 16; ++s) {           // 64 tasks = (d, j-half); 16 per wave
        int task = s * 4 + w;
        int td = task >> 1, half = task & 1;
        int j = half * 64 + lane;
        int bx = bin8(spad[j * 33 + td]);
        #pragma unroll
        for (int bb = 0; bb < 8; ++bb) {
            unsigned long long m = __ballot(bx == bb);
            if (lane == 0) {
                uint32_t* g = gmask + ((size_t)bt * 8 + bb) * 4 * DD + (half * 2) * DD + td;
                g[0] = (uint32_t)m;          // j quarter half*2
                g[DD] = (uint32_t)(m >> 32); // j quarter half*2+1
            }
        }
    }
}

// Plain __launch_bounds__(256): R3 proved a waves/EU hint forces spills.
// LDS: sval 16K (stride 32 -> value reads bank=d, conflict-free, R5-proven)
//    + sm 4K (sm[bin][q][d] -> census reads bank=d) + slist 16K = 36.9 KB -> 4 blocks/CU.
__global__ __launch_bounds__(256) void median_kernel(const float* __restrict__ xs,
                                                     const uint8_t* __restrict__ nbr,
                                                     const uint32_t* __restrict__ nmask32,
                                                     const uint32_t* __restrict__ gmask,
                                                     float* __restrict__ out) {
    __shared__ float sval[NN * DD];      // 16 KB frame, stride 32
    __shared__ uint32_t sm[8 * 4 * DD];  // 4 KB bin masks [bin][q][d]
    __shared__ uint32_t snm[NPB * 4];    // this block's node masks (quarters)
    __shared__ float slist[CAP * 256];   // 16 KB band values, column-major (bank tid%32)

    const int tid = threadIdx.x;
    const int g = blockIdx.x;
    const int ng = g % (NN / NPB);
    const int t  = (g / (NN / NPB)) % TT;
    const int b  = g / ((NN / NPB) * TT);
    const int n0 = ng * NPB;
    const int bt = b * TT + t;

    const int d = tid & (DD - 1);
    const int nl = tid >> 5;
    const int n = n0 + nl;
    const int pv = (t > 0) ? 1 : 0;       // wave-uniform
    const int nv = (t < TT - 1) ? 1 : 0;  // wave-uniform

    float xprev = 0.0f, xnext = 0.0f;
    if (pv) xprev = xs[(((size_t)(bt - 1) * NN) + n) * DD + d];
    if (nv) xnext = xs[(((size_t)(bt + 1) * NN) + n) * DD + d];

    // stage frame (float4, ds_write_b128) + bin masks (coalesced u32 copy) + node masks
    const float4* src4 = (const float4*)(xs + (size_t)bt * NN * DD);
    #pragma unroll
    for (int s = 0; s < 4; ++s) {
        int i4 = tid + (s << 8);
        ((float4*)sval)[i4] = src4[i4];
    }
    {
        const uint32_t* gsrc = gmask + (size_t)bt * 1024;
        #pragma unroll
        for (int s = 0; s < 4; ++s) sm[tid + (s << 8)] = gsrc[tid + (s << 8)];
    }
    if (tid < NPB * 4) snm[tid] = nmask32[n0 * 4 + tid];
    __syncthreads();

    uint32_t nm[4];
    #pragma unroll
    for (int q = 0; q < 4; ++q) nm[q] = snm[nl * 4 + q];
    const int deg = __popc(nm[0]) + __popc(nm[1]) + __popc(nm[2]) + __popc(nm[3]);
    const int k = deg + pv + nv;
    const uint32_t r = (uint32_t)((k - 1) >> 1);  // lower-median rank (0-based)
    const float INFV = __uint_as_float(0x7F800000u);
    const int tb0 = bin8(xprev), tb1 = bin8(xnext);  // guarded by pv/nv below

    // ---- census: 32 conflict-free LDS reads + popcounts; select bin holding rank r ----
    uint32_t cum = 0, lowcnt = 0, bandcnt = 0;
    int selbin = -1;
    #pragma unroll
    for (int bb = 0; bb < 8; ++bb) {
        uint32_t bc = __popc(nm[0] & sm[bb * 128 + d]) +
                      __popc(nm[1] & sm[bb * 128 + 32 + d]) +
                      __popc(nm[2] & sm[bb * 128 + 64 + d]) +
                      __popc(nm[3] & sm[bb * 128 + 96 + d]) +
                      (uint32_t)(pv && tb0 == bb) + (uint32_t)(nv && tb1 == bb);
        if (selbin < 0 && r < cum + bc) { selbin = bb; lowcnt = cum; bandcnt = bc; }
        cum += bc;
    }
    const bool fb = (bandcnt > CAP);     // only fallback: band too big
    const uint32_t rp = r - lowcnt;      // rank within band
    const bool tv0 = pv && (tb0 == selbin) && !fb;
    const bool tv1 = nv && (tb1 == selbin) && !fb;

    // ---- extraction: walk only the band's set bits into slist (~5 avg) ----
    int mc = 0;
    if (!fb) {
        #pragma unroll
        for (int q = 0; q < 4; ++q) {
            uint32_t m = nm[q] & sm[selbin * 128 + q * 32 + d];
            while (m) {
                int j = (q << 5) + __ffs(m) - 1;
                slist[mc * 256 + tid] = sval[(j << 5) + d];  // bank=d read, bank=tid write
                ++mc;
                m &= m - 1;
            }
        }
        if (tv0) { slist[mc * 256 + tid] = xprev; ++mc; }
        if (tv1) { slist[mc * 256 + tid] = xnext; ++mc; }
    }

    // ---- phase B: R5-proven streamed counting selection (ki/cn resident, 52 VGPR shape) ----
    float ki[CAP];
    uint32_t cn[CAP];
    #pragma unroll
    for (int u = 0; u < CAP; ++u) {
        float v = slist[u * 256 + tid];
        ki[u] = (u < mc) ? v : INFV;
        cn[u] = 0;
    }
    int mm = mc;  // wave max -> uniform trip count
    #pragma unroll
    for (int off = 32; off; off >>= 1) {
        int o = __shfl_xor(mm, off);
        mm = mm > o ? mm : o;
    }
    for (int j = 0; j < mm; ++j) {
        float x = slist[j * 256 + tid];
        x = (j < mc) ? x : INFV;
        #pragma unroll
        for (int u = 0; u < CAP; ++u) cn[u] += (x < ki[u]);
    }
    float result = 0.0f;
    bool found = fb;
    #pragma unroll
    for (int u = 0; u < CAP; ++u) {
        if (!found && u < mc && cn[u] == rp) { result = ki[u]; found = true; }
    }

    // ---- duplicate-median pass (exact multiset lower-median; ~never runs) ----
    if (__ballot(!found)) {
        uint32_t eq[CAP];
        #pragma unroll
        for (int u = 0; u < CAP; ++u) eq[u] = 0;
        for (int j = 0; j < mm; ++j) {
            float x = slist[j * 256 + tid];
            x = (j < mc) ? x : INFV;
            #pragma unroll
            for (int u = 0; u < CAP; ++u) eq[u] += (x == ki[u]);
        }
        #pragma unroll
        for (int u = 0; u < CAP; ++u) {
            if (!found && u < mc && cn[u] <= rp && rp < cn[u] + eq[u]) {
                result = ki[u]; found = true;
            }
        }
    }

    // ---- full fallback (band > CAP; ~1e-4 of lanes): exact scan over all k ----
    if (__ballot(fb)) {
        const uint8_t* nb = nbr + (size_t)n * NN;  // global u8 ids; only fb lanes load
        bool done = !fb;
        for (int i0 = 0; __ballot(!done) && i0 < 132; i0 += 4) {
            if (!done) {
                float k4[4]; uint32_t lt4[4], le4[4];
                #pragma unroll
                for (int u = 0; u < 4; ++u) {
                    int i = i0 + u;
                    float v;
                    if (i < deg) v = sval[(int)nb[i] * DD + d];
                    else if (i == deg && pv) v = xprev;
                    else if (i == deg + pv && i < k) v = xnext;
                    else v = INFV;
                    k4[u] = (i < k) ? v : INFV;
                    lt4[u] = 0; le4[u] = 0;
                }
                for (int j = 0; j < deg; ++j) {
                    float xv = sval[(int)nb[j] * DD + d];
                    #pragma unroll
                    for (int u = 0; u < 4; ++u) { lt4[u] += (xv < k4[u]); le4[u] += (xv <= k4[u]); }
                }
                if (pv) {
                    #pragma unroll
                    for (int u = 0; u < 4; ++u) { lt4[u] += (xprev < k4[u]); le4[u] += (xprev <= k4[u]); }
                }
                if (nv) {
                    #pragma unroll
                    for (int u = 0; u < 4; ++u) { lt4[u] += (xnext < k4[u]); le4[u] += (xnext <= k4[u]); }
                }
                #pragma unroll
                for (int u = 0; u < 4; ++u) {
                    if (!done && (i0 + u) < k && lt4[u] <= r && r < le4[u]) {
                        result = k4[u]; done = true;
                    }
                }
            }
        }
    }

    out[(((size_t)bt * NN) + n) * DD + d] = result;
}

extern "C" void kernel_launch(void* const* d_in, const int* in_sizes, int n_in,
                              void* d_out, int out_size, void* d_ws, size_t ws_size,
                              hipStream_t stream) {
    const float* xs = (const float*)d_in[0];
    const int* A = (const int*)d_in[1];
    float* out = (float*)d_out;

    // ws: nbr u8[16384] | nmask u64[256] (2 KB) | gmask u32[128*1024] (512 KB)
    uint8_t* nbr = (uint8_t*)d_ws;
    unsigned long long* nmask = (unsigned long long*)((char*)d_ws + NN * NN);
    uint32_t* gmask = (uint32_t*)((char*)d_ws + NN * NN + 2048);

    build_adj_kernel<<<NN, 64, 0, stream>>>(A, nbr, nmask);
    build_masks_kernel<<<BB * TT, 256, 0, stream>>>(xs, gmask);
    median_kernel<<<NBLK, 256, 0, stream>>>(xs, nbr, (const uint32_t*)nmask, gmask, out);
}

// Round 9
// 163.982 us; speedup vs baseline: 1.0567x; 1.0452x over previous
//
#include <hip/hip_runtime.h>
#include <stdint.h>
#include <math.h>

// Problem shape (fixed by reference): xs [B,T,N,D] fp32, A [1,N,N] int32
#define BB 4
#define TT 32
#define NN 128
#define DD 32
#define NPB 8                        // nodes per block (8 nodes x 32 d = 256 threads)
#define NBLK (BB * TT * (NN / NPB))  // 2048 blocks
#define CAP 16                       // band list capacity; overflow -> exact fallback

// Monotone non-decreasing 8-bin partition (bin0: x<-0.6 incl tail, bin7: x>=0.6
// incl tail, interior width 0.2). Any monotone partition gives exact rank
// selection; selected-bin overflow -> exact fallback. Proven R5-R7 (absmax 0).
__device__ __forceinline__ int bin8(float x) {
    int i = (int)fmaf(x, 5.0f, 4.0f);
    i = i < 0 ? 0 : i;
    return i > 7 ? 7 : i;
}

// Per-node: u8 neighbor id list (A2 scan + fallback) and 128-bit neighbor mask (census).
__global__ __launch_bounds__(64) void build_adj_kernel(const int* __restrict__ A,
                                                       uint8_t* __restrict__ nbr,
                                                       unsigned long long* __restrict__ nmask) {
    const int n = blockIdx.x;
    const int lane = threadIdx.x;  // 0..63
    const int* arow = A + n * NN;
    uint8_t* row = nbr + n * NN;
    const int j0 = lane, j1 = lane + 64;
    const bool b0 = (arow[j0] != 0) || (j0 == n);
    const bool b1 = (arow[j1] != 0) || (j1 == n);
    const unsigned long long m0 = __ballot(b0);
    const unsigned long long m1 = __ballot(b1);
    const unsigned long long lmask = (1ULL << lane) - 1ULL;
    const int c0 = __popcll(m0);
    if (b0) row[__popcll(m0 & lmask)] = (uint8_t)j0;
    if (b1) row[c0 + __popcll(m1 & lmask)] = (uint8_t)j1;
    if (lane == 0) { nmask[2 * n] = m0; nmask[2 * n + 1] = m1; }
}

// Per-frame bin-membership masks: gmask[bt][bin][q][d] (u32, q = j/32 quarter).
__global__ __launch_bounds__(256) void build_masks_kernel(const float* __restrict__ xs,
                                                          uint32_t* __restrict__ gmask) {
    __shared__ float spad[NN * 33];  // padded: j-across-lanes reads bank (j+d)%32
    const int bt = blockIdx.x;
    const int tid = threadIdx.x;
    const float4* src4 = (const float4*)(xs + (size_t)bt * NN * DD);
    #pragma unroll
    for (int s = 0; s < 4; ++s) {
        int i4 = tid + (s << 8);
        float4 v = src4[i4];
        int e = i4 << 2;
        float* dst = &spad[(e >> 5) * 33 + (e & 31)];
        dst[0] = v.x; dst[1] = v.y; dst[2] = v.z; dst[3] = v.w;
    }
    __syncthreads();
    const int w = tid >> 6, lane = tid & 63;
    for (int s = 0; s < 16; ++s) {           // 64 tasks = (d, j-half)
        int task = s * 4 + w;
        int td = task >> 1, half = task & 1;
        int j = half * 64 + lane;
        int bx = bin8(spad[j * 33 + td]);
        #pragma unroll
        for (int bb = 0; bb < 8; ++bb) {
            unsigned long long m = __ballot(bx == bb);
            if (lane == 0) {
                uint32_t* gp = gmask + ((size_t)bt * 8 + bb) * 4 * DD + (half * 2) * DD + td;
                gp[0] = (uint32_t)m;
                gp[DD] = (uint32_t)(m >> 32);
            }
        }
    }
}

// R5 skeleton (78us, 52 VGPR, 0 conflicts) with A1 replaced by popcount census.
// A2 stays the branchless always-store scan: 66 INDEPENDENT LDS reads (ILP,
// batchable ahead of waitcnt). R6/R7's divergent ffs bit-walk extraction was a
// serialized dependent chain -> 2x regression despite less work; do not reintroduce.
// Plain __launch_bounds__(256): R3 proved a waves/EU hint forces scratch spills.
__global__ __launch_bounds__(256) void median_kernel(const float* __restrict__ xs,
                                                     const uint8_t* __restrict__ nbr,
                                                     const uint32_t* __restrict__ nmask32,
                                                     const uint32_t* __restrict__ gmask,
                                                     float* __restrict__ out) {
    __shared__ float sval[NN * DD];           // 16 KB frame, stride 32 (value reads bank=d)
    __shared__ uint32_t snbr_w[NPB * NN / 4]; // 1 KB neighbor id lists (u8)
    __shared__ uint32_t sm[8 * 4 * DD];       // 4 KB bin masks [bin][q][d] (census reads bank=d)
    __shared__ uint32_t snm[NPB * 4];         // node masks (quarters)
    __shared__ float slist[(CAP + 1) * 256];  // 17 KB band values, column-major (bank tid%32)

    const int tid = threadIdx.x;
    const int g = blockIdx.x;
    const int ng = g % (NN / NPB);
    const int t  = (g / (NN / NPB)) % TT;
    const int b  = g / ((NN / NPB) * TT);
    const int n0 = ng * NPB;
    const int bt = b * TT + t;

    const int d = tid & (DD - 1);
    const int nl = tid >> 5;
    const int n = n0 + nl;
    const int pv = (t > 0) ? 1 : 0;       // wave-uniform
    const int nv = (t < TT - 1) ? 1 : 0;  // wave-uniform

    float xprev = 0.0f, xnext = 0.0f;
    if (pv) xprev = xs[(((size_t)(bt - 1) * NN) + n) * DD + d];
    if (nv) xnext = xs[(((size_t)(bt + 1) * NN) + n) * DD + d];

    // stage: frame (float4), neighbor lists, bin masks, node masks
    const float4* src4 = (const float4*)(xs + (size_t)bt * NN * DD);
    #pragma unroll
    for (int s = 0; s < 4; ++s) {
        int i4 = tid + (s << 8);
        ((float4*)sval)[i4] = src4[i4];
    }
    snbr_w[tid] = ((const uint32_t*)(nbr + (size_t)n0 * NN))[tid];
    {
        const uint32_t* gsrc = gmask + (size_t)bt * 1024;
        #pragma unroll
        for (int s = 0; s < 4; ++s) sm[tid + (s << 8)] = gsrc[tid + (s << 8)];
    }
    if (tid < NPB * 4) snm[tid] = nmask32[n0 * 4 + tid];
    __syncthreads();

    uint32_t nm[4];
    #pragma unroll
    for (int q = 0; q < 4; ++q) nm[q] = snm[nl * 4 + q];
    const int dg = __popc(nm[0]) + __popc(nm[1]) + __popc(nm[2]) + __popc(nm[3]);
    const int k = dg + pv + nv;
    const uint32_t r = (uint32_t)((k - 1) >> 1);  // lower-median rank (0-based)
    const float INFV = __uint_as_float(0x7F800000u);
    const int tb0 = bin8(xprev), tb1 = bin8(xnext);  // guarded by pv/nv

    // ---- census: 32 conflict-free LDS reads + popcounts (replaces R5's 66-read A1) ----
    uint32_t cum = 0, lowcnt = 0, bandcnt = 0;
    int selbin = -1;
    #pragma unroll
    for (int bb = 0; bb < 8; ++bb) {
        uint32_t bc = __popc(nm[0] & sm[bb * 128 + d]) +
                      __popc(nm[1] & sm[bb * 128 + 32 + d]) +
                      __popc(nm[2] & sm[bb * 128 + 64 + d]) +
                      __popc(nm[3] & sm[bb * 128 + 96 + d]) +
                      (uint32_t)(pv && tb0 == bb) + (uint32_t)(nv && tb1 == bb);
        if (selbin < 0 && r < cum + bc) { selbin = bb; lowcnt = cum; bandcnt = bc; }
        cum += bc;
    }
    const bool fb = (bandcnt > CAP);       // only fallback: band too big
    const uint32_t rp = r - lowcnt;        // rank within band
    const int storebin = fb ? -1 : selbin; // fb lanes store nothing (mc stays 0)
    const uint8_t* nb = (const uint8_t*)snbr_w + nl * NN;

    // ---- A2: R5's branchless always-store compaction (independent reads, ILP) ----
    int mc = 0;
    {
        int j = 0;
        for (; j + 4 <= dg; j += 4) {
            uint32_t nw = *(const uint32_t*)(nb + j);
            #pragma unroll
            for (int q = 0; q < 4; ++q) {
                float x = sval[((nw >> (q * 8)) & 0xFFu) * DD + d];
                int slot = mc > CAP ? CAP : mc;
                slist[slot * 256 + tid] = x;
                mc += (bin8(x) == storebin);
            }
        }
        for (; j < dg; ++j) {
            float x = sval[nb[j] * DD + d];
            int slot = mc > CAP ? CAP : mc;
            slist[slot * 256 + tid] = x;
            mc += (bin8(x) == storebin);
        }
        if (pv) {
            int slot = mc > CAP ? CAP : mc;
            slist[slot * 256 + tid] = xprev;
            mc += (tb0 == storebin);
        }
        if (nv) {
            int slot = mc > CAP ? CAP : mc;
            slist[slot * 256 + tid] = xnext;
            mc += (tb1 == storebin);
        }
    }

    // ---- phase B: R5-proven streamed counting selection ----
    float ki[CAP];
    uint32_t cn[CAP];
    #pragma unroll
    for (int u = 0; u < CAP; ++u) {
        float v = slist[u * 256 + tid];
        ki[u] = (u < mc) ? v : INFV;
        cn[u] = 0;
    }
    int mm = mc;  // wave max -> uniform trip count
    #pragma unroll
    for (int off = 32; off; off >>= 1) {
        int o = __shfl_xor(mm, off);
        mm = mm > o ? mm : o;
    }
    for (int j = 0; j < mm; ++j) {
        float x = slist[j * 256 + tid];
        x = (j < mc) ? x : INFV;
        #pragma unroll
        for (int u = 0; u < CAP; ++u) cn[u] += (x < ki[u]);
    }
    float result = 0.0f;
    bool found = fb;
    #pragma unroll
    for (int u = 0; u < CAP; ++u) {
        if (!found && u < mc && cn[u] == rp) { result = ki[u]; found = true; }
    }

    // ---- duplicate-median pass (exact multiset lower-median; ~never runs) ----
    if (__ballot(!found)) {
        uint32_t eq[CAP];
        #pragma unroll
        for (int u = 0; u < CAP; ++u) eq[u] = 0;
        for (int j = 0; j < mm; ++j) {
            float x = slist[j * 256 + tid];
            x = (j < mc) ? x : INFV;
            #pragma unroll
            for (int u = 0; u < CAP; ++u) eq[u] += (x == ki[u]);
        }
        #pragma unroll
        for (int u = 0; u < CAP; ++u) {
            if (!found && u < mc && cn[u] <= rp && rp < cn[u] + eq[u]) {
                result = ki[u]; found = true;
            }
        }
    }

    // ---- full fallback (band > CAP; ~1e-6/lane): exact scan over all k ----
    if (__ballot(fb)) {
        bool done = !fb;
        for (int i0 = 0; __ballot(!done) && i0 < 132; i0 += 4) {
            if (!done) {
                float k4[4]; uint32_t lt4[4], le4[4];
                #pragma unroll
                for (int u = 0; u < 4; ++u) {
                    int i = i0 + u;
                    float v;
                    if (i < dg) v = sval[(int)nb[i & 127] * DD + d];
                    else if (i == dg && pv) v = xprev;
                    else if (i == dg + pv && i < k) v = xnext;
                    else v = INFV;
                    k4[u] = (i < k) ? v : INFV;
                    lt4[u] = 0; le4[u] = 0;
                }
                for (int j = 0; j < dg; ++j) {
                    float xv = sval[nb[j] * DD + d];
                    #pragma unroll
                    for (int u = 0; u < 4; ++u) { lt4[u] += (xv < k4[u]); le4[u] += (xv <= k4[u]); }
                }
                if (pv) {
                    #pragma unroll
                    for (int u = 0; u < 4; ++u) { lt4[u] += (xprev < k4[u]); le4[u] += (xprev <= k4[u]); }
                }
                if (nv) {
                    #pragma unroll
                    for (int u = 0; u < 4; ++u) { lt4[u] += (xnext < k4[u]); le4[u] += (xnext <= k4[u]); }
                }
                #pragma unroll
                for (int u = 0; u < 4; ++u) {
                    if (!done && (i0 + u) < k && lt4[u] <= r && r < le4[u]) {
                        result = k4[u]; done = true;
                    }
                }
            }
        }
    }

    out[(((size_t)bt * NN) + n) * DD + d] = result;
}

extern "C" void kernel_launch(void* const* d_in, const int* in_sizes, int n_in,
                              void* d_out, int out_size, void* d_ws, size_t ws_size,
                              hipStream_t stream) {
    const float* xs = (const float*)d_in[0];
    const int* A = (const int*)d_in[1];
    float* out = (float*)d_out;

    // ws: nbr u8[16384] | nmask u64[256] (2 KB) | gmask u32[128*1024] (512 KB)
    uint8_t* nbr = (uint8_t*)d_ws;
    unsigned long long* nmask = (unsigned long long*)((char*)d_ws + NN * NN);
    uint32_t* gmask = (uint32_t*)((char*)d_ws + NN * NN + 2048);

    build_adj_kernel<<<NN, 64, 0, stream>>>(A, nbr, nmask);
    build_masks_kernel<<<BB * TT, 256, 0, stream>>>(xs, gmask);
    median_kernel<<<NBLK, 256, 0, stream>>>(xs, nbr, (const uint32_t*)nmask, gmask, out);
}